// Round 18
// baseline (1124.055 us; speedup 1.0000x reference)
//
#include <hip/hip_runtime.h>
#include <math.h>

#define NN 100000   // nodes
#define NE 1600000  // edges
#define NG 2048     // graphs
#define FIN 33      // input features
#define DD 256      // hidden dim

// binning constants
#define SH 8
#define NB ((NN + 255) >> 8)
#define CH 4096
#define PCAP 4608
#define ESCAP 6144

#define RBLKS ((NN + 255) / 256)  // 256-row GEMM blocks (391)
#define RB128 ((NN + 127) / 128)  // 128-row GEMM blocks (782)
#define NGRP  (RB128 * 2)         // het groups: 1564 (gemm sub-blocks)

typedef __attribute__((ext_vector_type(8))) short bf16x8;
typedef __attribute__((ext_vector_type(4))) float f32x4;

// ---- bf16 helpers (bit ops, RNE) ----
__device__ __forceinline__ float b2f(unsigned short u){
    union { unsigned int i; float f; } c; c.i = ((unsigned int)u) << 16; return c.f;
}
__device__ __forceinline__ unsigned short f2b(float f){
    union { float f; unsigned int u; } c; c.f = f;
    unsigned int r = c.u + 0x7fffu + ((c.u >> 16) & 1u);
    return (unsigned short)(r >> 16);
}

__device__ __forceinline__ float gelu_tanh(float x){
    float z = 0.7978845608028654f * (x + 0.044715f * x * x * x);
    return x / (1.0f + __expf(-2.0f * z));
}

// ---------------- CSR build via LDS-staged binning ----------------
__global__ __launch_bounds__(256) void k_bin(const int* __restrict__ src,
                                             const int* __restrict__ dst,
                                             int* __restrict__ gcur,
                                             int* __restrict__ pairs){
    __shared__ int cnt[NB];
    __shared__ int lb[NB];
    __shared__ int gbase[NB];
    __shared__ int sc[512];
    __shared__ int2 stage[CH];

    int t = threadIdx.x;
    for(int i = t; i < NB; i += 256) cnt[i] = 0;
    __syncthreads();

    int e0 = blockIdx.x * CH;
    int n = NE - e0; if(n > CH) n = CH;

    int  myb[16];
    int  myr[16];
    int2 myp[16];
    #pragma unroll
    for(int k = 0; k < 16; k++){
        int e = e0 + t + k * 256;
        if(e < NE){
            int s = src[e], d = dst[e];
            int b = d >> SH;
            myr[k] = atomicAdd(&cnt[b], 1);
            myb[k] = b;
            myp[k] = make_int2(s, d);
        } else myb[k] = -1;
    }
    __syncthreads();

    sc[t]       = (t       < NB) ? cnt[t]       : 0;
    sc[t + 256] = (t + 256 < NB) ? cnt[t + 256] : 0;
    __syncthreads();
    for(int off = 1; off < 512; off <<= 1){
        int a  = (t >= off)       ? sc[t - off]       : 0;
        int b2 = (t + 256 >= off) ? sc[t + 256 - off] : 0;
        __syncthreads();
        sc[t] += a; sc[t + 256] += b2;
        __syncthreads();
    }
    for(int i = t; i < NB; i += 256){
        lb[i] = sc[i] - cnt[i];
        int c = cnt[i];
        gbase[i] = (c > 0) ? atomicAdd(&gcur[i], c) : 0;
    }
    __syncthreads();

    #pragma unroll
    for(int k = 0; k < 16; k++){
        if(myb[k] >= 0) stage[lb[myb[k]] + myr[k]] = myp[k];
    }
    __syncthreads();

    for(int i = t; i < n; i += 256){
        int2 p = stage[i];
        int b = p.y >> SH;
        int tgt = gbase[b] + (i - lb[b]);
        if(tgt < PCAP) pairs[(size_t)b * PCAP + tgt] = p.x | ((p.y & 255) << 17);
    }
}

__global__ void k_sscan(const int* __restrict__ gcur, int* __restrict__ boff){
    __shared__ int s[512];
    int t = threadIdx.x;
    int v = 0;
    if(t < NB){ v = gcur[t]; if(v > PCAP) v = PCAP; }
    s[t] = v; __syncthreads();
    for(int off = 1; off < 512; off <<= 1){
        int u = (t >= off) ? s[t - off] : 0;
        __syncthreads();
        s[t] += u;
        __syncthreads();
    }
    if(t < NB) boff[t] = s[t] - v;
}

__global__ __launch_bounds__(256) void k_bcsr(const int* __restrict__ pairs,
                                              const int* __restrict__ gcur,
                                              const int* __restrict__ boff,
                                              int* __restrict__ deg,
                                              int* __restrict__ rs,
                                              int* __restrict__ esrc){
    __shared__ int hist[256];
    __shared__ int sc[256];
    __shared__ int cur2[256];
    __shared__ int est[ESCAP];

    int b = blockIdx.x;
    int t = threadIdx.x;
    int m = gcur[b]; if(m > PCAP) m = PCAP;
    int pstart = boff[b];
    const int* bp = pairs + (size_t)b * PCAP;

    hist[t] = 0;
    __syncthreads();
    for(int i = t; i < m; i += 256) atomicAdd(&hist[(bp[i] >> 17) & 255], 1);
    __syncthreads();

    sc[t] = hist[t]; __syncthreads();
    for(int off = 1; off < 256; off <<= 1){
        int u = (t >= off) ? sc[t - off] : 0;
        __syncthreads();
        sc[t] += u;
        __syncthreads();
    }
    int excl = sc[t] - hist[t];
    cur2[t] = excl;
    int node = (b << 8) + t;
    if(node < NN){
        deg[node] = hist[t];
        rs[node]  = pstart + excl;
    }
    __syncthreads();

    for(int i = t; i < m; i += 256){
        int p = bp[i];
        int pos = atomicAdd(&cur2[(p >> 17) & 255], 1);
        int s = p & 0x1FFFF;
        if(pos < ESCAP) est[pos] = s;
        else esrc[pstart + pos] = s;
    }
    __syncthreads();
    int lim = (m < ESCAP) ? m : ESCAP;
    for(int i = t; i < lim; i += 256) esrc[pstart + i] = est[i];
}

// ---------------- layer-0 input prep ----------------
__global__ void k_xpad(const float* __restrict__ x, unsigned short* __restrict__ xb){
    int idx = blockIdx.x * 256 + threadIdx.x;
    if(idx >= NN * 64) return;
    int n = idx >> 6, c = idx & 63;
    xb[idx] = (c < FIN) ? f2b(x[(size_t)n * FIN + c]) : 0;
}

__global__ void k_aggx(const unsigned short* __restrict__ xb, const int* __restrict__ rs,
                       const int* __restrict__ deg, const int* __restrict__ esrc,
                       unsigned short* __restrict__ axb){
    int wv = (blockIdx.x * blockDim.x + threadIdx.x) >> 6;
    int lane = threadIdx.x & 63;
    int node = wv * 4 + (lane >> 4);
    int l16 = lane & 15;
    if(node >= NN) return;
    int start = rs[node], cnt = deg[node];
    float a0 = 0.f, a1 = 0.f, a2 = 0.f, a3 = 0.f;
    const unsigned short* xp = xb + l16 * 4;
    int j = 0;
    for(; j + 4 <= cnt; j += 4){
        int e0 = esrc[start+j], e1 = esrc[start+j+1], e2 = esrc[start+j+2], e3 = esrc[start+j+3];
        ushort4 v0 = *(const ushort4*)(xp + (size_t)e0 * 64);
        ushort4 v1 = *(const ushort4*)(xp + (size_t)e1 * 64);
        ushort4 v2 = *(const ushort4*)(xp + (size_t)e2 * 64);
        ushort4 v3 = *(const ushort4*)(xp + (size_t)e3 * 64);
        a0 += (b2f(v0.x) + b2f(v1.x)) + (b2f(v2.x) + b2f(v3.x));
        a1 += (b2f(v0.y) + b2f(v1.y)) + (b2f(v2.y) + b2f(v3.y));
        a2 += (b2f(v0.z) + b2f(v1.z)) + (b2f(v2.z) + b2f(v3.z));
        a3 += (b2f(v0.w) + b2f(v1.w)) + (b2f(v2.w) + b2f(v3.w));
    }
    for(; j < cnt; j++){
        int e = esrc[start + j];
        ushort4 v = *(const ushort4*)(xp + (size_t)e * 64);
        a0 += b2f(v.x); a1 += b2f(v.y); a2 += b2f(v.z); a3 += b2f(v.w);
    }
    ushort4 o; o.x = f2b(a0); o.y = f2b(a1); o.z = f2b(a2); o.w = f2b(a3);
    *(ushort4*)(axb + (size_t)node * 64 + l16 * 4) = o;
}

// ---------------- weight prep ----------------
struct WPtrs { const float* w[6]; };

__global__ void k_wt6(WPtrs wp, unsigned short* __restrict__ btAll){
    __shared__ float s[16][17];
    const float* W = wp.w[blockIdx.z];
    unsigned short* Bt = btAll + (size_t)blockIdx.z * DD * DD;
    int tx = threadIdx.x, ty = threadIdx.y;
    int k = blockIdx.y * 16 + ty;
    int j = blockIdx.x * 16 + tx;
    s[ty][tx] = W[k * DD + j];
    __syncthreads();
    Bt[(size_t)(blockIdx.x * 16 + ty) * DD + blockIdx.y * 16 + tx] = f2b(s[tx][ty]);
}

struct W2Ptrs { const float* w[2]; };

__global__ void k_wt0(W2Ptrs wp, unsigned short* __restrict__ btAll){
    int idx = blockIdx.x * 256 + threadIdx.x;
    if(idx >= DD * 64) return;
    const float* W = wp.w[blockIdx.z];
    unsigned short* Bt = btAll + (size_t)blockIdx.z * DD * 64;
    int j = idx >> 6, k = idx & 63;
    Bt[idx] = (k < FIN) ? f2b(W[(size_t)k * DD + j]) : 0;
}

// ---- Bt [col][k] -> MFMA-fragment layout (verified round 17) ----
__global__ void k_bfrag(const unsigned short* __restrict__ Bt,
                        unsigned short* __restrict__ bf){
    int slot = blockIdx.x * 256 + threadIdx.x;
    if(slot >= 8192) return;
    int ks = slot >> 10;
    int rem = slot & 1023;
    int n = rem >> 6;
    int l = rem & 63;
    bf16x8 v = *(const bf16x8*)(Bt + (size_t)(n * 16 + (l & 15)) * DD + ks * 32 + (l >> 4) * 8);
    *(bf16x8*)(bf + (size_t)slot * 8) = v;
}

// ---------------- graph node counts ----------------
__global__ void k_cnt(const int* __restrict__ batch, int* __restrict__ gcnt){
    int i = blockIdx.x * 256 + threadIdx.x;
    if(i < NN) atomicAdd(&gcnt[batch[i]], 1);
}

// ---------------- hetero (LDS-FREE): agg (8/9) + no-LDS root GEMM (1/9) ----------------
// agg path: byte-identical pattern to the proven k_agg256 (2 nodes/wave).
// gemm path: R = h @ Wroot + bias via frag-layout B (verified r17), 128x128
// tile, 4 waves, zero LDS / zero barriers -> occupancy not LDS-capped (r12 fix).
__global__ __launch_bounds__(256) void k_het2(
    const unsigned short* __restrict__ h,
    const int* __restrict__ rs, const int* __restrict__ deg, const int* __restrict__ esrc,
    unsigned short* __restrict__ agg,
    const unsigned short* __restrict__ bfRoot,
    const float* __restrict__ bias,
    unsigned short* __restrict__ R)
{
    int bid = blockIdx.x;
    int q = bid / 9, rr = bid % 9;
    int t = threadIdx.x;
    int lane = t & 63;
    int w = t >> 6;

    if(rr < 8){
        // ---- agg path ----
        int node = (q * 8 + rr) * 8 + w * 2 + (lane >> 5);
        int l32 = lane & 31;
        if(node >= NN) return;
        int start = rs[node], cnt = deg[node];
        float a[8] = {0.f,0.f,0.f,0.f,0.f,0.f,0.f,0.f};
        const unsigned short* hp = h + l32 * 8;
        int j = 0;
        for(; j + 8 <= cnt; j += 8){
            bf16x8 v[8];
            #pragma unroll
            for(int qq = 0; qq < 8; qq++){
                int e = esrc[start + j + qq];
                v[qq] = *(const bf16x8*)(hp + (size_t)e * DD);
            }
            #pragma unroll
            for(int qq = 0; qq < 8; qq++)
                #pragma unroll
                for(int d = 0; d < 8; d++)
                    a[d] += b2f((unsigned short)v[qq][d]);
        }
        for(; j < cnt; j++){
            int e = esrc[start + j];
            bf16x8 v = *(const bf16x8*)(hp + (size_t)e * DD);
            #pragma unroll
            for(int d = 0; d < 8; d++) a[d] += b2f((unsigned short)v[d]);
        }
        bf16x8 o;
        #pragma unroll
        for(int d = 0; d < 8; d++) o[d] = (short)f2b(a[d]);
        *(bf16x8*)(agg + (size_t)node * DD + l32 * 8) = o;
    } else {
        // ---- root-GEMM path (no LDS, frag-B) ----
        int rblk = q >> 1, chalf = q & 1;
        int i0 = rblk * 128;
        int jbase = chalf * 128;
        int r16 = lane & 15, kg = lane >> 4;
        int baseRow = i0 + w * 32;

        f32x4 acc[2][8];
        #pragma unroll
        for(int m = 0; m < 2; m++)
            #pragma unroll
            for(int n = 0; n < 8; n++)
                acc[m][n] = (f32x4){0.f, 0.f, 0.f, 0.f};

        #pragma unroll
        for(int ksl = 0; ksl < 8; ksl++){
            int kk = ksl * 32 + kg * 8;
            bf16x8 af[2];
            #pragma unroll
            for(int m = 0; m < 2; m++){
                int gi = baseRow + m * 16 + r16;
                if(gi > NN - 1) gi = NN - 1;
                af[m] = *(const bf16x8*)(h + (size_t)gi * DD + kk);
            }
            const unsigned short* bpp = bfRoot + (size_t)((ksl * 16 + chalf * 8) * 64 + lane) * 8;
            #pragma unroll
            for(int n = 0; n < 8; n++){
                bf16x8 bfr = *(const bf16x8*)(bpp + (size_t)n * 64 * 8);
                acc[0][n] = __builtin_amdgcn_mfma_f32_16x16x32_bf16(af[0], bfr, acc[0][n], 0, 0, 0);
                acc[1][n] = __builtin_amdgcn_mfma_f32_16x16x32_bf16(af[1], bfr, acc[1][n], 0, 0, 0);
            }
        }

        int rg = kg * 4;
        #pragma unroll
        for(int n = 0; n < 8; n++){
            int gj = jbase + n * 16 + r16;
            float bb = bias[gj];
            #pragma unroll
            for(int m = 0; m < 2; m++){
                #pragma unroll
                for(int r = 0; r < 4; r++){
                    int gi = baseRow + m * 16 + rg + r;
                    if(gi < NN)
                        R[(size_t)gi * DD + gj] = f2b(acc[m][n][r] + bb);
                }
            }
        }
    }
}

// ---------------- layer-0 dual GEMM + rel GEMM (round-13 structure) ----------------
// DUAL=true: out = gelu(A0@B0 + A1@B1 + bias)   (layer 0)
// DUAL=false: out = gelu(A0@B0 + R) [R holds root+bias]; POOL fuses the head.
template<int KS, int AST, bool DUAL, bool POOL>
__global__ __launch_bounds__(512, 4) void k_gemm(
    const unsigned short* __restrict__ A0, const unsigned short* __restrict__ A1,
    const unsigned short* __restrict__ Bt0, const unsigned short* __restrict__ Bt1,
    const float* __restrict__ bias, unsigned short* __restrict__ out,
    unsigned short* __restrict__ R,
    const int* __restrict__ batch, const float* __restrict__ wout,
    float* __restrict__ gsum)
{
    constexpr int CK  = KS * 32;
    constexpr int BST = CK + 8;
    constexpr int SEG = CK / 8;
    constexpr int NMAT = DUAL ? 2 : 1;
    __shared__ unsigned short Bs[128 * BST];

    int t = threadIdx.x;
    int lane = t & 63;
    int w = t >> 6;
    int r16 = lane & 15;
    int kg  = lane >> 4;

    int bid = blockIdx.x;
    int rblk = (bid >> 4) * 8 + (bid & 7);
    int chalf = (bid >> 3) & 1;
    if(rblk >= RBLKS) return;
    int i0 = rblk * 256;
    int jbase = chalf * 128;
    int baseRow = i0 + w * 32;

    f32x4 acc[2][8];
    #pragma unroll
    for(int m = 0; m < 2; m++)
        #pragma unroll
        for(int n = 0; n < 8; n++)
            acc[m][n] = (f32x4){0.f, 0.f, 0.f, 0.f};

    auto loadA = [&](int gks, bf16x8* af){
        const unsigned short* Ap = (gks < KS) ? A0 : A1;
        int kk = ((gks < KS) ? gks : gks - KS) * 32 + kg * 8;
        #pragma unroll
        for(int m = 0; m < 2; m++){
            int gi = baseRow + m * 16 + r16;
            if(gi > NN - 1) gi = NN - 1;
            af[m] = *(const bf16x8*)(Ap + (size_t)gi * AST + kk);
        }
    };

    bf16x8 afb[2][2];
    loadA(0, afb[0]);
    loadA(1, afb[1]);

    #pragma unroll
    for(int c = 0; c < NMAT; c++){
        const unsigned short* Bp = c ? Bt1 : Bt0;
        if(c) __syncthreads();
        #pragma unroll
        for(int p = 0; p < (128 * SEG) / 512; p++){
            int idx = p * 512 + t;
            int row = idx / SEG;
            int k8 = (idx % SEG) * 8;
            *(bf16x8*)(&Bs[row * BST + k8]) =
                *(const bf16x8*)(Bp + (size_t)(jbase + row) * AST + k8);
        }
        __syncthreads();
        #pragma unroll
        for(int ksl = 0; ksl < KS; ksl++){
            int gks = c * KS + ksl;
            #pragma unroll
            for(int n = 0; n < 8; n++){
                bf16x8 bfr = *(const bf16x8*)(&Bs[(n * 16 + r16) * BST + ksl * 32 + kg * 8]);
                acc[0][n] = __builtin_amdgcn_mfma_f32_16x16x32_bf16(afb[gks & 1][0], bfr, acc[0][n], 0, 0, 0);
                acc[1][n] = __builtin_amdgcn_mfma_f32_16x16x32_bf16(afb[gks & 1][1], bfr, acc[1][n], 0, 0, 0);
            }
            if(gks + 2 < NMAT * KS) loadA(gks + 2, afb[gks & 1]);
        }
    }

    // epilogue: C/D layout col=lane&15, row=(lane>>4)*4+r  [m89-verified]
    int rg = kg * 4;
    if constexpr (!POOL){
        #pragma unroll
        for(int n = 0; n < 8; n++){
            int gj = jbase + n * 16 + r16;
            float bb = DUAL ? bias[gj] : 0.f;
            #pragma unroll
            for(int m = 0; m < 2; m++){
                #pragma unroll
                for(int r = 0; r < 4; r++){
                    int gi = baseRow + m * 16 + rg + r;
                    if(gi < NN){
                        size_t adr = (size_t)gi * DD + gj;
                        float v = acc[m][n][r] + (DUAL ? bb : b2f(R[adr]));
                        out[adr] = f2b(gelu_tanh(v));
                    }
                }
            }
        }
    } else {
        #pragma unroll
        for(int m = 0; m < 2; m++){
            #pragma unroll
            for(int r = 0; r < 4; r++){
                int gi = baseRow + m * 16 + rg + r;
                float s = 0.f;
                #pragma unroll
                for(int n = 0; n < 8; n++){
                    int gj = jbase + n * 16 + r16;
                    float rv = (gi < NN) ? b2f(R[(size_t)gi * DD + gj]) : 0.f;
                    s += gelu_tanh(acc[m][n][r] + rv) * wout[gj];
                }
                s += __shfl_xor(s, 1);
                s += __shfl_xor(s, 2);
                s += __shfl_xor(s, 4);
                s += __shfl_xor(s, 8);
                if(r16 == 0 && gi < NN)
                    atomicAdd(&gsum[batch[gi]], s);
            }
        }
    }
}

__global__ void k_final(const float* __restrict__ gsum, const int* __restrict__ gcnt,
                        const float* __restrict__ bout, float* __restrict__ out){
    int g = blockIdx.x * 256 + threadIdx.x;
    if(g < NG) out[g] = gsum[g] / fmaxf((float)gcnt[g], 1.f) + bout[0];
}

// ---------------- launch ----------------
extern "C" void kernel_launch(void* const* d_in, const int* in_sizes, int n_in,
                              void* d_out, int out_size, void* d_ws, size_t ws_size,
                              hipStream_t stream){
    const float* x       = (const float*)d_in[0];
    const int*   ei      = (const int*)d_in[1];
    const int*   src     = ei;
    const int*   dst     = ei + NE;
    const int*   batch   = (const int*)d_in[2];
    const float* w_rel0  = (const float*)d_in[3];
    const float* b_rel0  = (const float*)d_in[4];
    const float* w_root0 = (const float*)d_in[5];
    const float* w_rel1  = (const float*)d_in[6];
    const float* b_rel1  = (const float*)d_in[7];
    const float* w_root1 = (const float*)d_in[8];
    const float* w_rel2  = (const float*)d_in[9];
    const float* b_rel2  = (const float*)d_in[10];
    const float* w_root2 = (const float*)d_in[11];
    const float* w_rel3  = (const float*)d_in[12];
    const float* b_rel3  = (const float*)d_in[13];
    const float* w_root3 = (const float*)d_in[14];
    const float* w_out   = (const float*)d_in[15];
    const float* b_out   = (const float*)d_in[16];
    float* out = (float*)d_out;

    char* ws = (char*)d_ws;
    size_t off = 0;
    auto alloc = [&](size_t bytes) -> void* {
        void* p = ws + off;
        off = (off + bytes + 255) & ~(size_t)255;
        return p;
    };
    unsigned short* hA  = (unsigned short*)alloc((size_t)NN * DD * 2);
    unsigned short* hB  = (unsigned short*)alloc((size_t)NN * DD * 2);
    unsigned short* agg = (unsigned short*)alloc((size_t)NN * DD * 2);
    int*   deg  = (int*)alloc((size_t)NN * 4);
    int*   rs   = (int*)alloc((size_t)NN * 4);
    int*   esrc = (int*)alloc((size_t)NE * 4);
    int*   gcur = (int*)alloc(512 * 4);
    int*   boff = (int*)alloc(512 * 4);
    float* gsum = (float*)alloc((size_t)NG * 4);
    int*   gcnt = (int*)alloc((size_t)NG * 4);
    unsigned short* btAll  = (unsigned short*)alloc((size_t)6 * DD * DD * 2);
    unsigned short* bt0All = (unsigned short*)alloc((size_t)2 * DD * 64 * 2);
    unsigned short* bfRoot = (unsigned short*)alloc((size_t)3 * DD * DD * 2);  // frag tables
    (void)ws_size; (void)in_sizes; (void)n_in; (void)out_size;

    int* pairs = (int*)hB;                                  // CSR-build transient
    unsigned short* xb  = agg;                              // [NN,64] bf16
    unsigned short* axb = agg + (size_t)NN * 64 + 128;      // [NN,64] bf16

    // CSR build
    hipMemsetAsync(gcur, 0, 512 * 4, stream);
    k_bin<<<(NE + CH - 1) / CH, 256, 0, stream>>>(src, dst, gcur, pairs);
    k_sscan<<<1, 512, 0, stream>>>(gcur, boff);
    k_bcsr<<<NB, 256, 0, stream>>>(pairs, gcur, boff, deg, rs, esrc);

    // pool accumulators
    size_t poolBytes = (size_t)((char*)(gcnt + NG) - (char*)gsum);
    hipMemsetAsync(gsum, 0, poolBytes, stream);
    k_cnt<<<(NN + 255) / 256, 256, 0, stream>>>(batch, gcnt);

    // weight prep
    WPtrs wp; wp.w[0] = w_rel1; wp.w[1] = w_root1; wp.w[2] = w_rel2;
    wp.w[3] = w_root2; wp.w[4] = w_rel3; wp.w[5] = w_root3;
    k_wt6<<<dim3(16, 16, 6), dim3(16, 16), 0, stream>>>(wp, btAll);
    W2Ptrs w2; w2.w[0] = w_rel0; w2.w[1] = w_root0;
    k_wt0<<<dim3((DD * 64 + 255) / 256, 1, 2), 256, 0, stream>>>(w2, bt0All);
    k_xpad<<<(NN * 64 + 255) / 256, 256, 0, stream>>>(x, xb);

    unsigned short* bt[6];
    for(int i = 0; i < 6; i++) bt[i] = btAll + (size_t)i * DD * DD;
    unsigned short* bt0r = bt0All;
    unsigned short* bt0o = bt0All + (size_t)DD * 64;
    unsigned short* bfr1 = bfRoot;
    unsigned short* bfr2 = bfRoot + (size_t)DD * DD;
    unsigned short* bfr3 = bfRoot + (size_t)2 * DD * DD;
    k_bfrag<<<32, 256, 0, stream>>>(bt[1], bfr1);   // w_root1
    k_bfrag<<<32, 256, 0, stream>>>(bt[3], bfr2);   // w_root2
    k_bfrag<<<32, 256, 0, stream>>>(bt[5], bfr3);   // w_root3

    int hetGrid  = NGRP * 9;                  // 14076
    int gemmGrid = ((RBLKS + 7) / 8) * 16;

    // layer 0 (dual K=64)
    k_aggx<<<(NN + 15) / 16, 256, 0, stream>>>(xb, rs, deg, esrc, axb);
    k_gemm<2, 64, true, false><<<gemmGrid, 512, 0, stream>>>(axb, xb, bt0r, bt0o, b_rel0, hA,
                                                             nullptr, batch, w_out, gsum);
    // layer 1: het(agg + R->hB) ; rel(agg@Wrel + R -> hB)
    k_het2<<<hetGrid, 256, 0, stream>>>(hA, rs, deg, esrc, agg, bfr1, b_rel1, hB);
    k_gemm<8, 256, false, false><<<gemmGrid, 512, 0, stream>>>(agg, nullptr, bt[0], nullptr,
                                                               nullptr, hB, hB, batch, w_out, gsum);
    // layer 2
    k_het2<<<hetGrid, 256, 0, stream>>>(hB, rs, deg, esrc, agg, bfr2, b_rel2, hA);
    k_gemm<8, 256, false, false><<<gemmGrid, 512, 0, stream>>>(agg, nullptr, bt[2], nullptr,
                                                               nullptr, hA, hA, batch, w_out, gsum);
    // layer 3 (pool fused into rel)
    k_het2<<<hetGrid, 256, 0, stream>>>(hA, rs, deg, esrc, agg, bfr3, b_rel3, hB);
    k_gemm<8, 256, false, true><<<gemmGrid, 512, 0, stream>>>(agg, nullptr, bt[4], nullptr,
                                                              nullptr, hB, hB, batch, w_out, gsum);

    k_final<<<(NG + 255) / 256, 256, 0, stream>>>(gsum, gcnt, b_out, out);
}

// Round 19
// 739.598 us; speedup vs baseline: 1.5198x; 1.5198x over previous
//
#include <hip/hip_runtime.h>
#include <math.h>

#define NN 100000   // nodes
#define NE 1600000  // edges
#define NG 2048     // graphs
#define FIN 33      // input features
#define DD 256      // hidden dim

// binning constants
#define SH 8                      // bucket = dst >> 8 (256 nodes/bucket)
#define NB ((NN + 255) >> 8)      // 391 buckets
#define CH 4096                   // edges per k_bin block
#define PCAP 4608                 // per-bucket pair capacity
#define ESCAP 6144                // k_bcsr LDS esrc stage capacity

#define RBLKS ((NN + 255) / 256)  // GEMM row blocks

typedef __attribute__((ext_vector_type(8))) short bf16x8;
typedef __attribute__((ext_vector_type(4))) float f32x4;

// ---- bf16 helpers (bit ops, RNE) ----
__device__ __forceinline__ float b2f(unsigned short u){
    union { unsigned int i; float f; } c; c.i = ((unsigned int)u) << 16; return c.f;
}
__device__ __forceinline__ unsigned short f2b(float f){
    union { float f; unsigned int u; } c; c.f = f;
    unsigned int r = c.u + 0x7fffu + ((c.u >> 16) & 1u);
    return (unsigned short)(r >> 16);
}

// fast tanh-approx GELU: 0.5x(1+tanh(z)) == x * sigmoid(2z)
__device__ __forceinline__ float gelu_tanh(float x){
    float z = 0.7978845608028654f * (x + 0.044715f * x * x * x);
    return x / (1.0f + __expf(-2.0f * z));
}

// ---------------- CSR build via LDS-staged binning ----------------
// pairs entry: src (17 bits) | (dst & 255) << 17
__global__ __launch_bounds__(256) void k_bin(const int* __restrict__ src,
                                             const int* __restrict__ dst,
                                             int* __restrict__ gcur,
                                             int* __restrict__ pairs){
    __shared__ int cnt[NB];
    __shared__ int lb[NB];
    __shared__ int gbase[NB];
    __shared__ int sc[512];
    __shared__ int2 stage[CH];

    int t = threadIdx.x;
    for(int i = t; i < NB; i += 256) cnt[i] = 0;
    __syncthreads();

    int e0 = blockIdx.x * CH;
    int n = NE - e0; if(n > CH) n = CH;

    int  myb[16];
    int  myr[16];
    int2 myp[16];
    #pragma unroll
    for(int k = 0; k < 16; k++){
        int e = e0 + t + k * 256;
        if(e < NE){
            int s = src[e], d = dst[e];
            int b = d >> SH;
            myr[k] = atomicAdd(&cnt[b], 1);
            myb[k] = b;
            myp[k] = make_int2(s, d);
        } else myb[k] = -1;
    }
    __syncthreads();

    sc[t]       = (t       < NB) ? cnt[t]       : 0;
    sc[t + 256] = (t + 256 < NB) ? cnt[t + 256] : 0;
    __syncthreads();
    for(int off = 1; off < 512; off <<= 1){
        int a  = (t >= off)       ? sc[t - off]       : 0;
        int b2 = (t + 256 >= off) ? sc[t + 256 - off] : 0;
        __syncthreads();
        sc[t] += a; sc[t + 256] += b2;
        __syncthreads();
    }
    for(int i = t; i < NB; i += 256){
        lb[i] = sc[i] - cnt[i];
        int c = cnt[i];
        gbase[i] = (c > 0) ? atomicAdd(&gcur[i], c) : 0;
    }
    __syncthreads();

    #pragma unroll
    for(int k = 0; k < 16; k++){
        if(myb[k] >= 0) stage[lb[myb[k]] + myr[k]] = myp[k];
    }
    __syncthreads();

    for(int i = t; i < n; i += 256){
        int2 p = stage[i];
        int b = p.y >> SH;
        int tgt = gbase[b] + (i - lb[b]);
        if(tgt < PCAP) pairs[(size_t)b * PCAP + tgt] = p.x | ((p.y & 255) << 17);
    }
}

__global__ void k_sscan(const int* __restrict__ gcur, int* __restrict__ boff){
    __shared__ int s[512];
    int t = threadIdx.x;
    int v = 0;
    if(t < NB){ v = gcur[t]; if(v > PCAP) v = PCAP; }
    s[t] = v; __syncthreads();
    for(int off = 1; off < 512; off <<= 1){
        int u = (t >= off) ? s[t - off] : 0;
        __syncthreads();
        s[t] += u;
        __syncthreads();
    }
    if(t < NB) boff[t] = s[t] - v;
}

__global__ __launch_bounds__(256) void k_bcsr(const int* __restrict__ pairs,
                                              const int* __restrict__ gcur,
                                              const int* __restrict__ boff,
                                              int* __restrict__ deg,
                                              int* __restrict__ rs,
                                              int* __restrict__ esrc){
    __shared__ int hist[256];
    __shared__ int sc[256];
    __shared__ int cur2[256];
    __shared__ int est[ESCAP];

    int b = blockIdx.x;
    int t = threadIdx.x;
    int m = gcur[b]; if(m > PCAP) m = PCAP;
    int pstart = boff[b];
    const int* bp = pairs + (size_t)b * PCAP;

    hist[t] = 0;
    __syncthreads();
    for(int i = t; i < m; i += 256) atomicAdd(&hist[(bp[i] >> 17) & 255], 1);
    __syncthreads();

    sc[t] = hist[t]; __syncthreads();
    for(int off = 1; off < 256; off <<= 1){
        int u = (t >= off) ? sc[t - off] : 0;
        __syncthreads();
        sc[t] += u;
        __syncthreads();
    }
    int excl = sc[t] - hist[t];
    cur2[t] = excl;
    int node = (b << 8) + t;
    if(node < NN){
        deg[node] = hist[t];
        rs[node]  = pstart + excl;
    }
    __syncthreads();

    for(int i = t; i < m; i += 256){
        int p = bp[i];
        int pos = atomicAdd(&cur2[(p >> 17) & 255], 1);
        int s = p & 0x1FFFF;
        if(pos < ESCAP) est[pos] = s;
        else esrc[pstart + pos] = s;
    }
    __syncthreads();
    int lim = (m < ESCAP) ? m : ESCAP;
    for(int i = t; i < lim; i += 256) esrc[pstart + i] = est[i];
}

// ---------------- layer-0 input prep ----------------
__global__ void k_xpad(const float* __restrict__ x, unsigned short* __restrict__ xb){
    int idx = blockIdx.x * 256 + threadIdx.x;
    if(idx >= NN * 64) return;
    int n = idx >> 6, c = idx & 63;
    xb[idx] = (c < FIN) ? f2b(x[(size_t)n * FIN + c]) : 0;
}

__global__ void k_aggx(const unsigned short* __restrict__ xb, const int* __restrict__ rs,
                       const int* __restrict__ deg, const int* __restrict__ esrc,
                       unsigned short* __restrict__ axb){
    int wv = (blockIdx.x * blockDim.x + threadIdx.x) >> 6;
    int lane = threadIdx.x & 63;
    int node = wv * 4 + (lane >> 4);
    int l16 = lane & 15;
    if(node >= NN) return;
    int start = rs[node], cnt = deg[node];
    float a0 = 0.f, a1 = 0.f, a2 = 0.f, a3 = 0.f;
    const unsigned short* xp = xb + l16 * 4;
    int j = 0;
    for(; j + 4 <= cnt; j += 4){
        int e0 = esrc[start+j], e1 = esrc[start+j+1], e2 = esrc[start+j+2], e3 = esrc[start+j+3];
        ushort4 v0 = *(const ushort4*)(xp + (size_t)e0 * 64);
        ushort4 v1 = *(const ushort4*)(xp + (size_t)e1 * 64);
        ushort4 v2 = *(const ushort4*)(xp + (size_t)e2 * 64);
        ushort4 v3 = *(const ushort4*)(xp + (size_t)e3 * 64);
        a0 += (b2f(v0.x) + b2f(v1.x)) + (b2f(v2.x) + b2f(v3.x));
        a1 += (b2f(v0.y) + b2f(v1.y)) + (b2f(v2.y) + b2f(v3.y));
        a2 += (b2f(v0.z) + b2f(v1.z)) + (b2f(v2.z) + b2f(v3.z));
        a3 += (b2f(v0.w) + b2f(v1.w)) + (b2f(v2.w) + b2f(v3.w));
    }
    for(; j < cnt; j++){
        int e = esrc[start + j];
        ushort4 v = *(const ushort4*)(xp + (size_t)e * 64);
        a0 += b2f(v.x); a1 += b2f(v.y); a2 += b2f(v.z); a3 += b2f(v.w);
    }
    ushort4 o; o.x = f2b(a0); o.y = f2b(a1); o.z = f2b(a2); o.w = f2b(a3);
    *(ushort4*)(axb + (size_t)node * 64 + l16 * 4) = o;
}

// ---------------- aggregation layers 1-3 ----------------
__global__ void k_agg256(const unsigned short* __restrict__ h, const int* __restrict__ rs,
                         const int* __restrict__ deg, const int* __restrict__ esrc,
                         unsigned short* __restrict__ agg){
    int wv = (blockIdx.x * blockDim.x + threadIdx.x) >> 6;
    int lane = threadIdx.x & 63;
    int node = wv * 2 + (lane >> 5);
    int l32 = lane & 31;
    if(node >= NN) return;
    int start = rs[node], cnt = deg[node];
    float a[8] = {0.f,0.f,0.f,0.f,0.f,0.f,0.f,0.f};
    const unsigned short* hp = h + l32 * 8;
    int j = 0;
    for(; j + 8 <= cnt; j += 8){
        bf16x8 v[8];
        #pragma unroll
        for(int q = 0; q < 8; q++){
            int e = esrc[start + j + q];
            v[q] = *(const bf16x8*)(hp + (size_t)e * DD);
        }
        #pragma unroll
        for(int q = 0; q < 8; q++)
            #pragma unroll
            for(int d = 0; d < 8; d++)
                a[d] += b2f((unsigned short)v[q][d]);
    }
    for(; j < cnt; j++){
        int e = esrc[start + j];
        bf16x8 v = *(const bf16x8*)(hp + (size_t)e * DD);
        #pragma unroll
        for(int d = 0; d < 8; d++) a[d] += b2f((unsigned short)v[d]);
    }
    bf16x8 o;
    #pragma unroll
    for(int d = 0; d < 8; d++) o[d] = (short)f2b(a[d]);
    *(bf16x8*)(agg + (size_t)node * DD + l32 * 8) = o;
}

// ---------------- weight prep (merged launches) ----------------
struct WPtrs { const float* w[6]; };

__global__ void k_wt6(WPtrs wp, unsigned short* __restrict__ btAll){
    __shared__ float s[16][17];
    const float* W = wp.w[blockIdx.z];
    unsigned short* Bt = btAll + (size_t)blockIdx.z * DD * DD;
    int tx = threadIdx.x, ty = threadIdx.y;
    int k = blockIdx.y * 16 + ty;
    int j = blockIdx.x * 16 + tx;
    s[ty][tx] = W[k * DD + j];
    __syncthreads();
    Bt[(size_t)(blockIdx.x * 16 + ty) * DD + blockIdx.y * 16 + tx] = f2b(s[tx][ty]);
}

struct W2Ptrs { const float* w[2]; };

__global__ void k_wt0(W2Ptrs wp, unsigned short* __restrict__ btAll){
    int idx = blockIdx.x * 256 + threadIdx.x;
    if(idx >= DD * 64) return;
    const float* W = wp.w[blockIdx.z];
    unsigned short* Bt = btAll + (size_t)blockIdx.z * DD * 64;
    int j = idx >> 6, k = idx & 63;
    Bt[idx] = (k < FIN) ? f2b(W[(size_t)k * DD + j]) : 0;
}

// ---------------- graph node counts ----------------
__global__ void k_cnt(const int* __restrict__ batch, int* __restrict__ gcnt){
    int i = blockIdx.x * 256 + threadIdx.x;
    if(i < NN) atomicAdd(&gcnt[batch[i]], 1);
}

// ---------------- MFMA dual GEMM (round-13 best: full-K B-in-LDS, 2-deep ring) ----------------
// Block: 256 rows x 128 cols, 512 threads = 8 waves x 32 rows (m=2, n=8).
// B staged per matrix (full K) in LDS, one barrier between matrices; A direct
// from global with 2-deep register prefetch ring. No setprio. Fast-exp GELU.
template<int KS, int AST, bool POOL>
__global__ __launch_bounds__(512, 4) void k_mfma_gemm(
    const unsigned short* __restrict__ A0, const unsigned short* __restrict__ A1,
    const unsigned short* __restrict__ Bt0, const unsigned short* __restrict__ Bt1,
    const float* __restrict__ bias, unsigned short* __restrict__ out,
    const int* __restrict__ batch, const float* __restrict__ wout,
    float* __restrict__ gsum)
{
    constexpr int CK  = KS * 32;
    constexpr int BST = CK + 8;
    constexpr int SEG = CK / 8;
    __shared__ unsigned short Bs[128 * BST];

    int t = threadIdx.x;
    int lane = t & 63;
    int w = t >> 6;
    int r16 = lane & 15;
    int kg  = lane >> 4;

    int bid = blockIdx.x;
    int rblk = (bid >> 4) * 8 + (bid & 7);
    int chalf = (bid >> 3) & 1;
    if(rblk >= RBLKS) return;
    int i0 = rblk * 256;
    int jbase = chalf * 128;
    int baseRow = i0 + w * 32;

    f32x4 acc[2][8];
    #pragma unroll
    for(int m = 0; m < 2; m++)
        #pragma unroll
        for(int n = 0; n < 8; n++)
            acc[m][n] = (f32x4){0.f, 0.f, 0.f, 0.f};

    auto loadA = [&](int gks, bf16x8* af){
        const unsigned short* Ap = (gks < KS) ? A0 : A1;
        int kk = ((gks < KS) ? gks : gks - KS) * 32 + kg * 8;
        #pragma unroll
        for(int m = 0; m < 2; m++){
            int gi = baseRow + m * 16 + r16;
            if(gi > NN - 1) gi = NN - 1;
            af[m] = *(const bf16x8*)(Ap + (size_t)gi * AST + kk);
        }
    };

    bf16x8 afb[2][2];
    loadA(0, afb[0]);
    loadA(1, afb[1]);

    #pragma unroll
    for(int c = 0; c < 2; c++){
        const unsigned short* Bp = c ? Bt1 : Bt0;
        if(c) __syncthreads();
        #pragma unroll
        for(int p = 0; p < (128 * SEG) / 512; p++){
            int idx = p * 512 + t;
            int row = idx / SEG;
            int k8 = (idx % SEG) * 8;
            *(bf16x8*)(&Bs[row * BST + k8]) =
                *(const bf16x8*)(Bp + (size_t)(jbase + row) * AST + k8);
        }
        __syncthreads();
        #pragma unroll
        for(int ksl = 0; ksl < KS; ksl++){
            int gks = c * KS + ksl;
            #pragma unroll
            for(int n = 0; n < 8; n++){
                bf16x8 bfr = *(const bf16x8*)(&Bs[(n * 16 + r16) * BST + ksl * 32 + kg * 8]);
                acc[0][n] = __builtin_amdgcn_mfma_f32_16x16x32_bf16(afb[gks & 1][0], bfr, acc[0][n], 0, 0, 0);
                acc[1][n] = __builtin_amdgcn_mfma_f32_16x16x32_bf16(afb[gks & 1][1], bfr, acc[1][n], 0, 0, 0);
            }
            if(gks + 2 < 2 * KS) loadA(gks + 2, afb[gks & 1]);
        }
    }

    // epilogue: C/D layout col=lane&15, row=(lane>>4)*4+r  [m89-verified]
    int rg = kg * 4;
    if constexpr (!POOL){
        #pragma unroll
        for(int n = 0; n < 8; n++){
            int gj = jbase + n * 16 + r16;
            float bb = bias[gj];
            #pragma unroll
            for(int m = 0; m < 2; m++){
                #pragma unroll
                for(int r = 0; r < 4; r++){
                    int gi = baseRow + m * 16 + rg + r;
                    if(gi < NN)
                        out[(size_t)gi * DD + gj] = f2b(gelu_tanh(acc[m][n][r] + bb));
                }
            }
        }
    } else {
        #pragma unroll
        for(int m = 0; m < 2; m++){
            #pragma unroll
            for(int r = 0; r < 4; r++){
                float s = 0.f;
                #pragma unroll
                for(int n = 0; n < 8; n++){
                    int gj = jbase + n * 16 + r16;
                    s += gelu_tanh(acc[m][n][r] + bias[gj]) * wout[gj];
                }
                s += __shfl_xor(s, 1);
                s += __shfl_xor(s, 2);
                s += __shfl_xor(s, 4);
                s += __shfl_xor(s, 8);
                int gi = baseRow + m * 16 + rg + r;
                if(r16 == 0 && gi < NN)
                    atomicAdd(&gsum[batch[gi]], s);
            }
        }
    }
}

__global__ void k_final(const float* __restrict__ gsum, const int* __restrict__ gcnt,
                        const float* __restrict__ bout, float* __restrict__ out){
    int g = blockIdx.x * 256 + threadIdx.x;
    if(g < NG) out[g] = gsum[g] / fmaxf((float)gcnt[g], 1.f) + bout[0];
}

// ---------------- launch ----------------
extern "C" void kernel_launch(void* const* d_in, const int* in_sizes, int n_in,
                              void* d_out, int out_size, void* d_ws, size_t ws_size,
                              hipStream_t stream){
    const float* x       = (const float*)d_in[0];
    const int*   ei      = (const int*)d_in[1];
    const int*   src     = ei;
    const int*   dst     = ei + NE;
    const int*   batch   = (const int*)d_in[2];
    const float* w_rel0  = (const float*)d_in[3];
    const float* b_rel0  = (const float*)d_in[4];
    const float* w_root0 = (const float*)d_in[5];
    const float* w_rel1  = (const float*)d_in[6];
    const float* b_rel1  = (const float*)d_in[7];
    const float* w_root1 = (const float*)d_in[8];
    const float* w_rel2  = (const float*)d_in[9];
    const float* b_rel2  = (const float*)d_in[10];
    const float* w_root2 = (const float*)d_in[11];
    const float* w_rel3  = (const float*)d_in[12];
    const float* b_rel3  = (const float*)d_in[13];
    const float* w_root3 = (const float*)d_in[14];
    const float* w_out   = (const float*)d_in[15];
    const float* b_out   = (const float*)d_in[16];
    float* out = (float*)d_out;

    char* ws = (char*)d_ws;
    size_t off = 0;
    auto alloc = [&](size_t bytes) -> void* {
        void* p = ws + off;
        off = (off + bytes + 255) & ~(size_t)255;
        return p;
    };
    unsigned short* hA  = (unsigned short*)alloc((size_t)NN * DD * 2);
    unsigned short* hB  = (unsigned short*)alloc((size_t)NN * DD * 2);
    unsigned short* agg = (unsigned short*)alloc((size_t)NN * DD * 2);
    int*   deg  = (int*)alloc((size_t)NN * 4);
    int*   rs   = (int*)alloc((size_t)NN * 4);
    int*   esrc = (int*)alloc((size_t)NE * 4);
    int*   gcur = (int*)alloc(512 * 4);
    int*   boff = (int*)alloc(512 * 4);
    float* gsum = (float*)alloc((size_t)NG * 4);
    int*   gcnt = (int*)alloc((size_t)NG * 4);
    unsigned short* btAll = (unsigned short*)alloc((size_t)6 * DD * DD * 2);
    unsigned short* bt0All = (unsigned short*)alloc((size_t)2 * DD * 64 * 2);
    (void)ws_size; (void)in_sizes; (void)n_in; (void)out_size;

    int* pairs = (int*)hB;                                  // CSR-build transient
    unsigned short* xb  = agg;                              // [NN,64] bf16
    unsigned short* axb = agg + (size_t)NN * 64 + 128;      // [NN,64] bf16

    // CSR build via binning
    hipMemsetAsync(gcur, 0, 512 * 4, stream);
    k_bin<<<(NE + CH - 1) / CH, 256, 0, stream>>>(src, dst, gcur, pairs);
    k_sscan<<<1, 512, 0, stream>>>(gcur, boff);
    k_bcsr<<<NB, 256, 0, stream>>>(pairs, gcur, boff, deg, rs, esrc);

    // pool accumulators (must precede the fused layer-3 GEMM)
    size_t poolBytes = (size_t)((char*)(gcnt + NG) - (char*)gsum);
    hipMemsetAsync(gsum, 0, poolBytes, stream);
    k_cnt<<<(NN + 255) / 256, 256, 0, stream>>>(batch, gcnt);

    // weight prep (3 launches)
    WPtrs wp; wp.w[0] = w_rel1; wp.w[1] = w_root1; wp.w[2] = w_rel2;
    wp.w[3] = w_root2; wp.w[4] = w_rel3; wp.w[5] = w_root3;
    k_wt6<<<dim3(16, 16, 6), dim3(16, 16), 0, stream>>>(wp, btAll);
    W2Ptrs w2; w2.w[0] = w_rel0; w2.w[1] = w_root0;
    k_wt0<<<dim3((DD * 64 + 255) / 256, 1, 2), 256, 0, stream>>>(w2, bt0All);
    k_xpad<<<(NN * 64 + 255) / 256, 256, 0, stream>>>(x, xb);

    unsigned short* bt[6];
    for(int i = 0; i < 6; i++) bt[i] = btAll + (size_t)i * DD * DD;
    unsigned short* bt0r = bt0All;
    unsigned short* bt0o = bt0All + (size_t)DD * 64;

    int agg2Grid = (NN * 32 + 255) / 256;
    int gemmGrid = ((RBLKS + 7) / 8) * 16;   // 8 rblks x 2 col-halves per group

    // layer 0
    k_aggx<<<(NN + 15) / 16, 256, 0, stream>>>(xb, rs, deg, esrc, axb);
    k_mfma_gemm<2, 64, false><<<gemmGrid, 512, 0, stream>>>(axb, xb, bt0r, bt0o, b_rel0, hA,
                                                            batch, w_out, gsum);
    // layers 1..2
    k_agg256<<<agg2Grid, 256, 0, stream>>>(hA, rs, deg, esrc, agg);
    k_mfma_gemm<8, 256, false><<<gemmGrid, 512, 0, stream>>>(agg, hA, bt[0], bt[1], b_rel1, hB,
                                                             batch, w_out, gsum);
    k_agg256<<<agg2Grid, 256, 0, stream>>>(hB, rs, deg, esrc, agg);
    k_mfma_gemm<8, 256, false><<<gemmGrid, 512, 0, stream>>>(agg, hB, bt[2], bt[3], b_rel2, hA,
                                                             batch, w_out, gsum);
    // layer 3: fused mean-pool head (no h store)
    k_agg256<<<agg2Grid, 256, 0, stream>>>(hA, rs, deg, esrc, agg);
    k_mfma_gemm<8, 256, true><<<gemmGrid, 512, 0, stream>>>(agg, hA, bt[4], bt[5], b_rel3, hB,
                                                            batch, w_out, gsum);

    k_final<<<(NG + 255) / 256, 256, 0, stream>>>(gsum, gcnt, b_out, out);
}